// Round 11
// baseline (462.175 us; speedup 1.0000x reference)
//
#include <hip/hip_runtime.h>
#include <hip/hip_bf16.h>

// Problem: B=2, T=2048, C=2048, H=16, HD=128.
// Round 13: attn V-destaging + rope-epilogue bank-conflict fix.
//  1. attn: V read DIRECT from global (catalog m169: drop V-staging when KV
//     L2-fits; our V=1MB/head, 16 same-head blocks share an XCD). PV B-frag
//     Vt[d][kt+kc*32+quad*8..+7] is a contiguous short8 in the [d][t] layout
//     -> drop-in global read, byte-identical values. Removes half the gll16
//     drain, 16 KB LDS (41->25 KB), 16 ds_read_b128/wave/iter.
//  2. gemm_bt<1> Q/K rope epilogue: XOR col swizzle (store col^(quad<<4),
//     load col^(((rowL>>2)&3)<<4); (rowL>>2)&3==quad -> same slot). Kills the
//     524K 8-way write conflicts; bijective; values identical.
// Else identical to r12 (r10-measured): fused rope+cvt3, r9-proven attn
// core, round-0 gemm_bt (at its m97-structure ceiling, MfmaUtil 37%).

typedef __attribute__((ext_vector_type(8))) short short8;   // 8 bf16 MFMA A/B frag
typedef __attribute__((ext_vector_type(4))) float f32x4;    // MFMA C/D frag

#define B_  2
#define T_  2048
#define C_  2048
#define H_  16
#define HD_ 128

#define LGKM0()   asm volatile("s_waitcnt lgkmcnt(0)" ::: "memory")

__device__ __forceinline__ float bf2f(unsigned short u) {
  union { unsigned int i; float f; } v; v.i = ((unsigned int)u) << 16; return v.f;
}
__device__ __forceinline__ unsigned short f2bf(float f) {
  union { float f; unsigned int i; } v; v.f = f;
  unsigned int x = v.i;
  return (unsigned short)((x + 0x7fffu + ((x >> 16) & 1u)) >> 16);  // RNE
}
__device__ __forceinline__ float fexp2(float x) {
#if __has_builtin(__builtin_amdgcn_exp2f)
  return __builtin_amdgcn_exp2f(x);
#else
  return exp2f(x);
#endif
}

// async 16B global->LDS; lds base wave-uniform, lane l lands at base + l*16.
__device__ __forceinline__ void gll16(const unsigned short* g, unsigned short* lds_base) {
  __builtin_amdgcn_global_load_lds(
      (const __attribute__((address_space(1))) void*)g,
      (__attribute__((address_space(3))) void*)lds_base, 16, 0, 0);
}

__device__ __forceinline__ ushort4 cvt4(float4 v) {
  ushort4 h;
  h.x = f2bf(v.x); h.y = f2bf(v.y); h.z = f2bf(v.z); h.w = f2bf(v.w);
  return h;
}

// ---------------------------------------------------------------------------
// f32 -> bf16 converts. cvt_k: single buffer. cvt2_k: x+Wqkv (contiguous
// dst). cvt3_k: x+Wqkv (contiguous dst) + Wo (separate dst).
// ---------------------------------------------------------------------------
__global__ void cvt_k(const float* __restrict__ src, unsigned short* __restrict__ dst, int n4)
{
  int i = blockIdx.x * blockDim.x + threadIdx.x;
  if (i < n4) ((ushort4*)dst)[i] = cvt4(((const float4*)src)[i]);
}

__global__ void cvt2_k(const float* __restrict__ a, const float* __restrict__ b,
                       unsigned short* __restrict__ dab, int na4, int n4)
{
  int i = blockIdx.x * blockDim.x + threadIdx.x;
  if (i >= n4) return;
  float4 v = (i < na4) ? ((const float4*)a)[i] : ((const float4*)b)[i - na4];
  ((ushort4*)dab)[i] = cvt4(v);
}

__global__ void cvt3_k(const float* __restrict__ a, const float* __restrict__ b,
                       const float* __restrict__ c,
                       unsigned short* __restrict__ dab, unsigned short* __restrict__ dc,
                       int na4, int nab4, int n4)
{
  int i = blockIdx.x * blockDim.x + threadIdx.x;
  if (i >= n4) return;
  if (i < nab4) {
    float4 v = (i < na4) ? ((const float4*)a)[i] : ((const float4*)b)[i - na4];
    ((ushort4*)dab)[i] = cvt4(v);
  } else {
    ((ushort4*)dc)[i - nab4] = cvt4(((const float4*)c)[i - nab4]);
  }
}

// ---------------------------------------------------------------------------
// m97-style NT GEMM (bf16 x bf16): C[M][N] = A[M][K]*Bw[N][K]^T + bias.
// 128x128 tile, BK=64, 2x2 waves of 64x64, 4x4 16x16x32 MFMA frags,
// global_load_lds width=16 staging, XOR-swizzled LDS columns.
// MODE 0: f32 row-major store. MODE 1: bf16 qkv scatter:
//   Q,K -> [bh][t][d] with FUSED ROPE (LDS pair-exchange, XOR-swizzled
//   against bank conflicts; value-identical to the old rope_k chain);
//   V -> TRANSPOSED [bh][d][t].
// MFMA layouts (HW-verified m89/m91): A: A[m=lane&15][k=quad*8+j];
// B: B[k=quad*8+j][n=lane&15]; C/D: col=lane&15, row=quad*4+reg.
// ---------------------------------------------------------------------------
template<int MODE>
__global__ __launch_bounds__(256, 2)
void gemm_bt(const unsigned short* __restrict__ A,
             const unsigned short* __restrict__ Bw,
             const float* __restrict__ bias,
             float* __restrict__ Cout,
             unsigned short* __restrict__ Qb,
             unsigned short* __restrict__ Kb,
             unsigned short* __restrict__ Vb,
             int N, int K)
{
  __shared__ unsigned short Lsh[128 * 128];   // 32 KB: Al|Bl during K-loop,
  unsigned short* const Al = Lsh;             // 128x128 rope tile in epilogue
  unsigned short* const Bl = Lsh + 128 * 64;
  const int tid  = threadIdx.x;
  const int wave = tid >> 6, lane = tid & 63;
  const int quad = lane >> 4, l15 = lane & 15;
  const int wm = wave >> 1, wn = wave & 1;
  const int n0 = blockIdx.x * 128, m0 = blockIdx.y * 128;

  f32x4 acc[4][4];
#pragma unroll
  for (int i = 0; i < 4; i++)
#pragma unroll
    for (int j = 0; j < 4; j++) acc[i][j] = (f32x4){0.f, 0.f, 0.f, 0.f};

  for (int k0 = 0; k0 < K; k0 += 64) {
    __syncthreads();
    const unsigned short* Ag = A + (size_t)m0 * K + k0;
    const unsigned short* Bg = Bw + (size_t)n0 * K + k0;
#pragma unroll
    for (int i = 0; i < 4; i++) {
      int cc = i * 256 + wave * 64 + lane;      // LDS 16B-slot id, 0..1023
      int r = cc >> 3;
      int c8 = (cc & 7) ^ (r & 7);              // swizzled source col chunk
      gll16(Ag + (size_t)r * K + c8 * 8, &Al[(i * 4 + wave) * 512]);
      gll16(Bg + (size_t)r * K + c8 * 8, &Bl[(i * 4 + wave) * 512]);
    }
    __syncthreads();
#pragma unroll
    for (int kc = 0; kc < 2; kc++) {
      // swizzled col offset: row&7 == l15&7 for all mi/ni (offsets are *8)
      const int csw = (((kc * 4 + quad) ^ (l15 & 7)) * 8);
      short8 af[4], bfr[4];
#pragma unroll
      for (int mi = 0; mi < 4; mi++)
        af[mi] = *(const short8*)&Al[(wm * 64 + mi * 16 + l15) * 64 + csw];
#pragma unroll
      for (int ni = 0; ni < 4; ni++)
        bfr[ni] = *(const short8*)&Bl[(wn * 64 + ni * 16 + l15) * 64 + csw];
#pragma unroll
      for (int mi = 0; mi < 4; mi++)
#pragma unroll
        for (int ni = 0; ni < 4; ni++)
          acc[mi][ni] = __builtin_amdgcn_mfma_f32_16x16x32_bf16(af[mi], bfr[ni], acc[mi][ni], 0, 0, 0);
    }
  }

  if constexpr (MODE == 0) {
#pragma unroll
    for (int mi = 0; mi < 4; mi++)
#pragma unroll
      for (int ni = 0; ni < 4; ni++) {
        int col = n0 + wn * 64 + ni * 16 + l15;
        float bv = bias[col];
#pragma unroll
        for (int r = 0; r < 4; r++) {
          int row = m0 + wm * 64 + mi * 16 + quad * 4 + r;
          Cout[(size_t)row * N + col] = acc[mi][ni][r] + bv;
        }
      }
  } else {
    const int which = n0 >> 11;      // block never straddles Q/K/V
    const int h = (n0 >> 7) & 15;    // block covers exactly one head
    unsigned short* P = (which == 0) ? Qb : (which == 1) ? Kb : Vb;
    if (which == 2) {
      // V: transposed scatter (unchanged)
#pragma unroll
      for (int mi = 0; mi < 4; mi++)
#pragma unroll
        for (int ni = 0; ni < 4; ni++) {
          int d = wn * 64 + ni * 16 + l15;
          float bv = bias[n0 + d];
#pragma unroll
          for (int r = 0; r < 4; r++) {
            int m = m0 + wm * 64 + mi * 16 + quad * 4 + r;
            int b = m >> 11, t = m & (T_ - 1);
            P[((size_t)((b * H_ + h) * HD_ + d)) * T_ + t] = f2bf(acc[mi][ni][r] + bv);
          }
        }
    } else {
      // Q/K: fused rope via LDS pair-exchange, XOR-swizzled (store col ^
      // (quad<<4); load col ^ (((rowL>>2)&3)<<4); (rowL>>2)&3 == quad for
      // every writer, so load hits the writer's slot. Bijective per row;
      // both phases 2-way bank aliasing (free). Values identical to rope_k.
      __syncthreads();                 // all Al/Bl reads complete
#pragma unroll
      for (int mi = 0; mi < 4; mi++)
#pragma unroll
        for (int ni = 0; ni < 4; ni++) {
          int colL = wn * 64 + ni * 16 + l15;
          float bv = bias[n0 + colL];
#pragma unroll
          for (int r = 0; r < 4; r++) {
            int rowL = wm * 64 + mi * 16 + quad * 4 + r;
            Lsh[rowL * 128 + (colL ^ (quad << 4))] = f2bf(acc[mi][ni][r] + bv);
          }
        }
      __syncthreads();
      const int d  = tid & 63;
      const int c0 = tid >> 6;
      const float theta = expf(-exp2f((float)d) * 0.07195578415606394f); // ln(1e4)/128
      const float QS = 0.08838834764831845f * 1.4426950408889634f; // 1/sqrt(128)*log2(e)
#pragma unroll
      for (int i = 0; i < 32; i++) {
        int rowL = c0 * 32 + i;
        int m = m0 + rowL;
        int b = m >> 11, t = m & (T_ - 1);
        float ang = (float)(t + 1) * theta;
        float cc = cosf(ang), ss = sinf(ang);
        int xr = ((rowL >> 2) & 3) << 4;
        float q0 = bf2f(Lsh[rowL * 128 + (d ^ xr)]);
        float q1 = bf2f(Lsh[rowL * 128 + (d ^ xr) + 64]);
        float o0 = q0 * cc - q1 * ss;
        float o1 = q1 * cc + q0 * ss;
        if (which == 0) { o0 *= QS; o1 *= QS; }
        size_t base = ((size_t)((b * H_ + h) * T_ + t)) * HD_;
        P[base + d]      = f2bf(o0);
        P[base + 64 + d] = f2bf(o1);
      }
    }
  }
}

// ---------------------------------------------------------------------------
// RoPE in-place on bf16 Q and K — retained for the fallback (gemm_nt) path.
// ---------------------------------------------------------------------------
__global__ void rope_k(unsigned short* __restrict__ Q, unsigned short* __restrict__ K)
{
  const int tid = threadIdx.x;
  const int w = tid >> 6, l = tid & 63;
  const int r = blockIdx.x * 4 + w;
  const int t = r & (T_ - 1);
  const float pos = (float)(t + 1);
  const float theta = expf(-exp2f((float)l) * 0.07195578415606394f); // ln(1e4)/128
  const float ang = pos * theta;
  const float c = cosf(ang), s = sinf(ang);
  const float QS = 0.08838834764831845f * 1.4426950408889634f; // 1/sqrt(128)*log2(e)
  const size_t base = (size_t)r * HD_;

  float q0 = bf2f(Q[base + l]), q1 = bf2f(Q[base + l + 64]);
  Q[base + l]      = f2bf((q0 * c - q1 * s) * QS);
  Q[base + l + 64] = f2bf((q1 * c + q0 * s) * QS);
  float k0 = bf2f(K[base + l]), k1 = bf2f(K[base + l + 64]);
  K[base + l]      = f2bf(k0 * c - k1 * s);
  K[base + l + 64] = f2bf(k1 * c + k0 * s);
}

// ---------------------------------------------------------------------------
// Flash-style causal attention — r9-proven core, V read DIRECT from global
// (m169: drop V-staging when L2-fits; V=1MB/head, 16 same-head blocks share
// an XCD since blk spacing 32 == 0 mod 8). K stays LDS-staged (XOR swizzle).
// Grid 512 = (bh 32) x (qpair 16); each block does Q-tiles qp*64 and
// (31-qp)*64 -> uniform 33 k-iters. 4 waves x 16 rows. LDS 25 KB.
// Kl [64][128]: slot (r,c16) holds global (r, c16^(r&15)); read col-chunk
// (kc*4+quad)^l15 -> 2-way aliasing (free).
// ---------------------------------------------------------------------------
__global__ __launch_bounds__(256, 2)
void attn_k(const unsigned short* __restrict__ Q,
            const unsigned short* __restrict__ K,
            const unsigned short* __restrict__ Vt_g,
            unsigned short* __restrict__ AO)
{
  __shared__ unsigned short Kl[64 * 128];
  __shared__ unsigned short Pl[4 * 16 * 72];

  const int tid  = threadIdx.x;
  const int wave = tid >> 6, lane = tid & 63;
  const int quad = lane >> 4, l15 = lane & 15;
  const int blk = blockIdx.x;
  const int bh = (blk & 7) + 8 * ((blk >> 3) & 3);
  const int qp = (blk >> 5) & 15;
  const unsigned short* Qh = Q    + (size_t)bh * T_ * HD_;
  const unsigned short* Kh = K    + (size_t)bh * T_ * HD_;
  const unsigned short* Vh = Vt_g + (size_t)bh * T_ * HD_;  // [d][t]
  const int b = bh >> 4, h = bh & 15;

#pragma unroll
  for (int tile = 0; tile < 2; tile++) {
    const int q0 = (tile == 0 ? qp : 31 - qp) * 64;
    const int wq = q0 + wave * 16;
    short8 qf[4];
#pragma unroll
    for (int kc = 0; kc < 4; kc++)
      qf[kc] = *(const short8*)&Qh[(size_t)(wq + l15) * HD_ + kc * 32 + quad * 8];

    f32x4 oacc[8];
#pragma unroll
    for (int n = 0; n < 8; n++) oacc[n] = (f32x4){0.f, 0.f, 0.f, 0.f};
    float mst[4], lst[4];
#pragma unroll
    for (int r = 0; r < 4; r++) { mst[r] = -1e30f; lst[r] = 0.f; }

    const int niter = (q0 >> 6) + 1;
    for (int it = 0; it < niter; it++) {
      const int kt = it * 64;
      __syncthreads();
      // stage K [64][128] only, source-col XOR swizzle (V is global-direct)
#pragma unroll
      for (int i = 0; i < 4; i++) {
        int cc = i * 256 + wave * 64 + lane;  // slot id 0..1023
        int kr = cc >> 4, kcs = (cc & 15) ^ (kr & 15);
        gll16(Kh + (size_t)(kt + kr) * HD_ + kcs * 8, &Kl[(i * 4 + wave) * 512]);
      }
      __syncthreads();

      // S' = (Q*s) K^T
      f32x4 sa[4];
#pragma unroll
      for (int ni = 0; ni < 4; ni++) sa[ni] = (f32x4){0.f, 0.f, 0.f, 0.f};
#pragma unroll
      for (int kc = 0; kc < 4; kc++) {
        const int cswK = (((kc * 4 + quad) ^ l15) * 8);
        short8 bfr[4];
#pragma unroll
        for (int ni = 0; ni < 4; ni++)
          bfr[ni] = *(const short8*)&Kl[(ni * 16 + l15) * HD_ + cswK];
#pragma unroll
        for (int ni = 0; ni < 4; ni++)
          sa[ni] = __builtin_amdgcn_mfma_f32_16x16x32_bf16(qf[kc], bfr[ni], sa[ni], 0, 0, 0);
      }

      if (kt == q0) {   // causal mask, diagonal tile only (uniform branch)
#pragma unroll
        for (int ni = 0; ni < 4; ni++) {
          int gcol = kt + ni * 16 + l15;
#pragma unroll
          for (int r = 0; r < 4; r++) {
            int grow = wq + quad * 4 + r;
            if (gcol > grow) sa[ni][r] = -1e30f;
          }
        }
      }

      // online softmax, base-2. (sa <= rmax <= mst by construction -> no
      // clamps; exp2 of -1e30 underflows to 0 correctly.)
      float rmax[4] = {-1e30f, -1e30f, -1e30f, -1e30f};
#pragma unroll
      for (int ni = 0; ni < 4; ni++)
#pragma unroll
        for (int r = 0; r < 4; r++) rmax[r] = fmaxf(rmax[r], sa[ni][r]);
#pragma unroll
      for (int r = 0; r < 4; r++)
#pragma unroll
        for (int off = 1; off < 16; off <<= 1)
          rmax[r] = fmaxf(rmax[r], __shfl_xor(rmax[r], off));
      // alpha-skip: if no row's max grew, alpha == 1 exactly -> skip the
      // rescale (bitwise-identical result).
      int grew = (rmax[0] > mst[0]) | (rmax[1] > mst[1]) |
                 (rmax[2] > mst[2]) | (rmax[3] > mst[3]);
      if (__any(grew)) {
        float alpha[4];
#pragma unroll
        for (int r = 0; r < 4; r++) {
          float mnew = fmaxf(mst[r], rmax[r]);
          alpha[r] = fexp2(mst[r] - mnew);
          mst[r] = mnew;
          lst[r] *= alpha[r];
        }
#pragma unroll
        for (int nv = 0; nv < 8; nv++)
#pragma unroll
          for (int r = 0; r < 4; r++) oacc[nv][r] *= alpha[r];
      }
      float rsum[4] = {0.f, 0.f, 0.f, 0.f};
#pragma unroll
      for (int ni = 0; ni < 4; ni++)
#pragma unroll
        for (int r = 0; r < 4; r++) {
          float p = fexp2(sa[ni][r] - mst[r]);
          sa[ni][r] = p;
          rsum[r] += p;
        }
#pragma unroll
      for (int r = 0; r < 4; r++) {
#pragma unroll
        for (int off = 1; off < 16; off <<= 1)
          rsum[r] += __shfl_xor(rsum[r], off);
        lst[r] += rsum[r];
      }
      // P -> LDS (wave-private region; per-wave DS ops in-order, so
      // lgkmcnt(0) suffices -- no block barrier between write and read).
#pragma unroll
      for (int ni = 0; ni < 4; ni++)
#pragma unroll
        for (int r = 0; r < 4; r++)
          Pl[wave * 16 * 72 + (quad * 4 + r) * 72 + ni * 16 + l15] = f2bf(sa[ni][r]);
      LGKM0();

      // O += P V   (V direct from global: Vt[d][t] row-contiguous short8)
      short8 pf[2];
#pragma unroll
      for (int kc = 0; kc < 2; kc++)
        pf[kc] = *(const short8*)&Pl[wave * 16 * 72 + l15 * 72 + kc * 32 + quad * 8];
#pragma unroll
      for (int kc = 0; kc < 2; kc++) {
        short8 vb[8];
#pragma unroll
        for (int nv = 0; nv < 8; nv++)
          vb[nv] = *(const short8*)&Vh[(size_t)(nv * 16 + l15) * T_ + kt + kc * 32 + quad * 8];
#pragma unroll
        for (int nv = 0; nv < 8; nv++)
          oacc[nv] = __builtin_amdgcn_mfma_f32_16x16x32_bf16(pf[kc], vb[nv], oacc[nv], 0, 0, 0);
      }
    }

    float linv[4];
#pragma unroll
    for (int r = 0; r < 4; r++) linv[r] = 1.0f / fmaxf(lst[r], 1e-20f);
#pragma unroll
    for (int nv = 0; nv < 8; nv++)
#pragma unroll
      for (int r = 0; r < 4; r++) {
        int t = wq + quad * 4 + r;
        int d = nv * 16 + l15;
        AO[((size_t)(b * T_ + t)) * C_ + h * HD_ + d] = f2bf(oacc[nv][r] * linv[r]);
      }
  }
}

// ---------------------------------------------------------------------------
// Fallback GEMM (f32 sources converted during staging) — only if ws too small.
// ---------------------------------------------------------------------------
template<int A32, int B32, int MODE>
__global__ __launch_bounds__(256, 2)
void gemm_nt(const void* __restrict__ Ap, const void* __restrict__ Bp,
             const float* __restrict__ bias,
             float* __restrict__ Cout,
             unsigned short* __restrict__ Qb,
             unsigned short* __restrict__ Kb,
             unsigned short* __restrict__ Vb,
             int N, int K)
{
  __shared__ unsigned short Al[128 * 72];
  __shared__ unsigned short Bl[128 * 72];
  const int tid  = threadIdx.x;
  const int wave = tid >> 6, lane = tid & 63;
  const int quad = lane >> 4, l15 = lane & 15;
  const int wm = wave >> 1, wn = wave & 1;
  const int n0 = blockIdx.x * 128, m0 = blockIdx.y * 128;

  f32x4 acc[4][4];
#pragma unroll
  for (int i = 0; i < 4; i++)
#pragma unroll
    for (int j = 0; j < 4; j++) acc[i][j] = (f32x4){0.f, 0.f, 0.f, 0.f};

  for (int k0 = 0; k0 < K; k0 += 64) {
    __syncthreads();
    if constexpr (A32) {
      const float* A = (const float*)Ap;
#pragma unroll
      for (int i = 0; i < 8; i++) {
        int cid = tid + i * 256;
        int r = cid >> 4, c = cid & 15;
        float4 v = *(const float4*)&A[(size_t)(m0 + r) * K + k0 + c * 4];
        *(ushort4*)&Al[r * 72 + c * 4] = cvt4(v);
      }
    } else {
      const unsigned short* A = (const unsigned short*)Ap;
#pragma unroll
      for (int i = 0; i < 4; i++) {
        int cid = tid + i * 256;
        int r = cid >> 3, c = cid & 7;
        *(float4*)&Al[r * 72 + c * 8] =
            *(const float4*)&A[(size_t)(m0 + r) * K + k0 + c * 8];
      }
    }
    if constexpr (B32) {
      const float* Bm = (const float*)Bp;
#pragma unroll
      for (int i = 0; i < 8; i++) {
        int cid = tid + i * 256;
        int r = cid >> 4, c = cid & 15;
        float4 v = *(const float4*)&Bm[(size_t)(n0 + r) * K + k0 + c * 4];
        *(ushort4*)&Bl[r * 72 + c * 4] = cvt4(v);
      }
    } else {
      const unsigned short* Bm = (const unsigned short*)Bp;
#pragma unroll
      for (int i = 0; i < 4; i++) {
        int cid = tid + i * 256;
        int r = cid >> 3, c = cid & 7;
        *(float4*)&Bl[r * 72 + c * 8] =
            *(const float4*)&Bm[(size_t)(n0 + r) * K + k0 + c * 8];
      }
    }
    __syncthreads();
#pragma unroll
    for (int kc = 0; kc < 2; kc++) {
      short8 af[4], bfr[4];
#pragma unroll
      for (int mi = 0; mi < 4; mi++)
        af[mi] = *(const short8*)&Al[(wm * 64 + mi * 16 + l15) * 72 + kc * 32 + quad * 8];
#pragma unroll
      for (int ni = 0; ni < 4; ni++)
        bfr[ni] = *(const short8*)&Bl[(wn * 64 + ni * 16 + l15) * 72 + kc * 32 + quad * 8];
#pragma unroll
      for (int mi = 0; mi < 4; mi++)
#pragma unroll
        for (int ni = 0; ni < 4; ni++)
          acc[mi][ni] = __builtin_amdgcn_mfma_f32_16x16x32_bf16(af[mi], bfr[ni], acc[mi][ni], 0, 0, 0);
    }
  }

  if constexpr (MODE == 0) {
#pragma unroll
    for (int mi = 0; mi < 4; mi++)
#pragma unroll
      for (int ni = 0; ni < 4; ni++) {
        int col = n0 + wn * 64 + ni * 16 + l15;
        float bv = bias[col];
#pragma unroll
        for (int r = 0; r < 4; r++) {
          int row = m0 + wm * 64 + mi * 16 + quad * 4 + r;
          Cout[(size_t)row * N + col] = acc[mi][ni][r] + bv;
        }
      }
  } else {
    int which = n0 >> 11;
    int h = (n0 >> 7) & 15;
    unsigned short* P = (which == 0) ? Qb : (which == 1) ? Kb : Vb;
#pragma unroll
    for (int mi = 0; mi < 4; mi++)
#pragma unroll
      for (int ni = 0; ni < 4; ni++) {
        int d = wn * 64 + ni * 16 + l15;
        float bv = bias[n0 + d];
#pragma unroll
        for (int r = 0; r < 4; r++) {
          int m = m0 + wm * 64 + mi * 16 + quad * 4 + r;
          int b = m >> 11, t = m & (T_ - 1);
          size_t addr = (which == 2)
              ? ((size_t)((b * H_ + h) * HD_ + d)) * T_ + t
              : ((size_t)((b * H_ + h) * T_ + t)) * HD_ + d;
          P[addr] = f2bf(acc[mi][ni][r] + bv);
        }
      }
  }
}

// ---------------------------------------------------------------------------
extern "C" void kernel_launch(void* const* d_in, const int* in_sizes, int n_in,
                              void* d_out, int out_size, void* d_ws, size_t ws_size,
                              hipStream_t stream)
{
  const float* x    = (const float*)d_in[0];  // [2,2048,2048] f32
  const float* Wqkv = (const float*)d_in[1];  // [6144,2048]   f32
  const float* bqkv = (const float*)d_in[2];  // [6144]        f32
  const float* Wo   = (const float*)d_in[3];  // [2048,2048]   f32
  const float* bo   = (const float*)d_in[4];  // [2048]        f32
  float* out = (float*)d_out;                 // [2,2048,2048] f32

  const size_t SZ   = (size_t)B_ * H_ * T_ * HD_;   // 8,388,608
  const size_t NX   = SZ;
  const size_t NWQ  = (size_t)3 * C_ * C_;
  const size_t NWO  = (size_t)C_ * C_;
  unsigned short* ws = (unsigned short*)d_ws;

  dim3 blk(256, 1, 1);
  const size_t need  = (NX + NWQ + 3 * SZ) * sizeof(unsigned short);  // 92.3 MB
  const size_t need2 = need + NWO * sizeof(unsigned short);           // +8.4 MB

  if (ws_size >= need) {
    unsigned short* xb    = ws;
    unsigned short* Wqkvb = xb + NX;
    unsigned short* Qb    = Wqkvb + NWQ;
    unsigned short* Kb    = Qb + SZ;
    unsigned short* Vb    = Kb + SZ;      // transposed [bh][d][t]
    unsigned short* AO    = xb;           // alias: x dead after QKV GEMM
    const bool sepWo = (ws_size >= need2);
    unsigned short* Wob = sepWo ? (Vb + SZ) : Wqkvb;  // alias if tight

    if (sepWo) {
      // single convert pass for x, Wqkv, Wo (4 launches total)
      cvt3_k<<<dim3((unsigned)((NX + NWQ + NWO) / 1024)), blk, 0, stream>>>(
          x, Wqkv, Wo, xb, Wob,
          (int)(NX / 4), (int)((NX + NWQ) / 4), (int)((NX + NWQ + NWO) / 4));
      gemm_bt<1><<<dim3(48, 32, 1), blk, 0, stream>>>(
          xb, Wqkvb, bqkv, nullptr, Qb, Kb, Vb, 6144, 2048);  // rope fused
    } else {
      cvt2_k<<<dim3((unsigned)((NX + NWQ) / 1024)), blk, 0, stream>>>(
          x, Wqkv, xb, (int)(NX / 4), (int)((NX + NWQ) / 4));
      gemm_bt<1><<<dim3(48, 32, 1), blk, 0, stream>>>(
          xb, Wqkvb, bqkv, nullptr, Qb, Kb, Vb, 6144, 2048);  // rope fused
      cvt_k<<<dim3((unsigned)(NWO / 1024)), blk, 0, stream>>>(Wo, Wob, (int)(NWO / 4));
    }
    attn_k<<<dim3(512, 1, 1), blk, 0, stream>>>(Qb, Kb, Vb, AO);
    gemm_bt<0><<<dim3(16, 32, 1), blk, 0, stream>>>(
        AO, Wob, bo, out, nullptr, nullptr, nullptr, 2048, 2048);
  } else {
    unsigned short* Qb = ws;
    unsigned short* Kb = Qb + SZ;
    unsigned short* Vb = Kb + SZ;
    unsigned short* AO = Vb + SZ;
    gemm_nt<1, 1, 1><<<dim3(48, 32, 1), blk, 0, stream>>>(
        (const void*)x, (const void*)Wqkv, bqkv, nullptr, Qb, Kb, Vb, 6144, 2048);
    rope_k<<<dim3((B_ * H_ * T_) / 4, 1, 1), blk, 0, stream>>>(Qb, Kb);
    attn_k<<<dim3(512, 1, 1), blk, 0, stream>>>(Qb, Kb, Vb, AO);
    gemm_nt<0, 1, 0><<<dim3(16, 32, 1), blk, 0, stream>>>(
        (const void*)AO, (const void*)Wo, bo, out, nullptr, nullptr, nullptr, 2048, 2048);
  }
}